// Round 1
// baseline (3847.581 us; speedup 1.0000x reference)
//
#include <hip/hip_runtime.h>
#include <math.h>

#define NN 50000
#define NE 800000
#define FN 92
#define FE 50
#define HID 128

// ---------------------------------------------------------------- helpers
__device__ __forceinline__ float sigmoidf_(float x) {
    return 1.0f / (1.0f + __expf(-x));
}
__device__ __forceinline__ float softplusf_(float x) {
    // jax.nn.softplus = max(x,0) + log1p(exp(-|x|))
    return fmaxf(x, 0.0f) + __logf(1.0f + __expf(-fabsf(x)));
}
__device__ __forceinline__ float f4get(const float4& v, int i) {
    return i == 0 ? v.x : i == 1 ? v.y : i == 2 ? v.z : v.w;
}
__device__ __forceinline__ void atomAddF(float* p, float v) {
#if defined(__gfx90a__) || defined(__gfx940__) || defined(__gfx941__) || defined(__gfx942__) || defined(__gfx950__)
    unsafeAtomicAdd(p, v);
#else
    atomicAdd(p, v);
#endif
}

// ---------------------------------------------------------------- GEMM
// C[M x 128] = act(A[M x K] @ B[K x 128] + bias), LDS-free, 64x64 block tile,
// 256 threads, 4x4 register tile per thread. B/A reuse served by the
// coalescer (same-address lanes dedup to one request) + L1/L2.
template<int K, int LDA, bool BIAS, bool RELU>
__global__ __launch_bounds__(256) void k_gemm(
    const float* __restrict__ A, int M,
    const float* __restrict__ B,          // K x 128 row-major
    const float* __restrict__ bias,       // 128 (or null)
    float* __restrict__ C0, int ldc0)
{
    const int t  = threadIdx.x;
    const int r0 = blockIdx.x * 64;
    const int cb = blockIdx.y * 64;
    const int tx = t & 15;
    const int ty = t >> 4;
    const int c4 = cb + (tx << 2);        // global col of 4-col group
    const int rr = r0 + (ty << 2);        // global row of 4-row group

    // clamp OOB rows to row 0 (loaded but never stored)
    int ri[4];
#pragma unroll
    for (int i = 0; i < 4; ++i) ri[i] = (rr + i < M) ? (rr + i) : 0;

    float acc[4][4] = {};
#pragma unroll 2
    for (int k = 0; k < K; k += 4) {
        float4 a[4], b[4];
#pragma unroll
        for (int i = 0; i < 4; ++i)
            a[i] = *(const float4*)&A[(size_t)ri[i] * LDA + k];
#pragma unroll
        for (int j = 0; j < 4; ++j)
            b[j] = *(const float4*)&B[(size_t)(k + j) * 128 + c4];
#pragma unroll
        for (int kk = 0; kk < 4; ++kk)
#pragma unroll
            for (int i = 0; i < 4; ++i)
#pragma unroll
                for (int j = 0; j < 4; ++j)
                    acc[i][j] = fmaf(f4get(a[i], kk), f4get(b[kk], j), acc[i][j]);
    }

    float4 bb = make_float4(0.f, 0.f, 0.f, 0.f);
    if (BIAS) bb = *(const float4*)&bias[c4];
#pragma unroll
    for (int i = 0; i < 4; ++i) {
        const int r = rr + i;
        if (r < M) {
            float4 o;
            o.x = acc[i][0] + bb.x;
            o.y = acc[i][1] + bb.y;
            o.z = acc[i][2] + bb.z;
            o.w = acc[i][3] + bb.w;
            if (RELU) {
                o.x = fmaxf(o.x, 0.f); o.y = fmaxf(o.y, 0.f);
                o.z = fmaxf(o.z, 0.f); o.w = fmaxf(o.w, 0.f);
            }
            *(float4*)&C0[(size_t)r * ldc0 + c4] = o;
        }
    }
}

// ---------------------------------------------------------------- edge kernel
// Per batch of 32 edges (per block iteration):
//   pf[c] = P[d][c]     + P[s][128+c] + ea[e].Wfe[:,c] + bf[c]
//   ps[c] = P[d][256+c] + P[s][384+c] + ea[e].Wse[:,c] + bs[c]
//   msg   = sigmoid(pf) * softplus(ps);  acc[d][:] += msg (atomic)
// Thread map: eg = t>>6 (wave = 8 edges), which = (t&63)>>5 (0:f / 1:s),
// c4 = 4-col group. sigmoid/softplus partners are lanes l and l^32 of the
// same wave -> __shfl_xor exchange, no LDS round trip.
__global__ __launch_bounds__(256) void k_edge_msg(
    const float* __restrict__ P,     // [NN][512]
    const float* __restrict__ ea,    // [NE][50]
    const float* __restrict__ Wfe,   // [50][128]
    const float* __restrict__ Wse,   // [50][128]
    const float* __restrict__ bfl,   // [128]
    const float* __restrict__ bsl,   // [128]
    const int*   __restrict__ esrc,
    const int*   __restrict__ edst,
    float*       __restrict__ accp)  // [NN][128], pre-initialized to h
{
    __shared__ float Wl[2 * 50 * 128];   // 51.2 KB
    __shared__ float eal[32 * 50];       // 6.4 KB
    __shared__ int   il[2][32];

    const int t = threadIdx.x;

    // stage Wf_e / Ws_e once per block
    for (int idx = t; idx < 1600; idx += 256) {
        const int k = idx >> 5, cq = (idx & 31) << 2;
        *(float4*)&Wl[k * 128 + cq]        = *(const float4*)&Wfe[k * 128 + cq];
        *(float4*)&Wl[6400 + k * 128 + cq] = *(const float4*)&Wse[k * 128 + cq];
    }

    const int cq_   = t & 63;
    const int which = cq_ >> 5;            // 0 -> pf (sigmoid), 1 -> ps (softplus)
    const int c4    = (cq_ & 31) << 2;
    const int eg    = t >> 6;              // wave id -> edge group of 8
    const float* bias = which ? bsl : bfl;
    const float4 bb = *(const float4*)&bias[c4];
    const float* WlW = Wl + which * 6400;
    const int pofs = which * 256;

    const int NB = NE / 32;                // 25000, exact
    for (int b = blockIdx.x; b < NB; b += gridDim.x) {
        const int e0 = b * 32;
        for (int idx = t; idx < 1600; idx += 256)
            eal[idx] = ea[(size_t)e0 * 50 + idx];
        if (t < 32)      il[0][t]      = esrc[e0 + t];
        else if (t < 64) il[1][t - 32] = edst[e0 + t - 32];
        __syncthreads();

        float m[8][4];
        // init with gathers + bias
#pragma unroll
        for (int ii = 0; ii < 8; ++ii) {
            const int le = eg * 8 + ii;
            const int d = il[1][le], s = il[0][le];
            const float4 g1 = *(const float4*)&P[(size_t)d * 512 + pofs + c4];
            const float4 g2 = *(const float4*)&P[(size_t)s * 512 + pofs + 128 + c4];
            m[ii][0] = g1.x + g2.x + bb.x;
            m[ii][1] = g1.y + g2.y + bb.y;
            m[ii][2] = g1.z + g2.z + bb.z;
            m[ii][3] = g1.w + g2.w + bb.w;
        }
        // + ea @ W_e   (8 edges x 4 cols in registers)
        for (int k = 0; k < 50; ++k) {
            const float4 w = *(const float4*)&WlW[k * 128 + c4];
#pragma unroll
            for (int ii = 0; ii < 8; ++ii) {
                const float e = eal[(eg * 8 + ii) * 50 + k];
                m[ii][0] = fmaf(e, w.x, m[ii][0]);
                m[ii][1] = fmaf(e, w.y, m[ii][1]);
                m[ii][2] = fmaf(e, w.z, m[ii][2]);
                m[ii][3] = fmaf(e, w.w, m[ii][3]);
            }
        }
        // activation + cross-half exchange + product
#pragma unroll
        for (int ii = 0; ii < 8; ++ii) {
#pragma unroll
            for (int j = 0; j < 4; ++j) {
                const float v = m[ii][j];
                const float a = which ? softplusf_(v) : sigmoidf_(v);
                const float o = __shfl_xor(a, 32, 64);
                m[ii][j] = a * o;          // sigmoid(pf)*softplus(ps), both halves
            }
        }
        // scatter: half 0 handles edges 0..3 of its group, half 1 edges 4..7
        if (which == 0) {
#pragma unroll
            for (int q = 0; q < 4; ++q) {
                const int d = il[1][eg * 8 + q];
                float* p = accp + (size_t)d * 128 + c4;
                atomAddF(p + 0, m[q][0]);
                atomAddF(p + 1, m[q][1]);
                atomAddF(p + 2, m[q][2]);
                atomAddF(p + 3, m[q][3]);
            }
        } else {
#pragma unroll
            for (int q = 0; q < 4; ++q) {
                const int d = il[1][eg * 8 + 4 + q];
                float* p = accp + (size_t)d * 128 + c4;
                atomAddF(p + 0, m[4 + q][0]);
                atomAddF(p + 1, m[4 + q][1]);
                atomAddF(p + 2, m[4 + q][2]);
                atomAddF(p + 3, m[4 + q][3]);
            }
        }
        __syncthreads();   // protect eal/il before next batch
    }
}

// ---------------------------------------------------------------- launcher
extern "C" void kernel_launch(void* const* d_in, const int* in_sizes, int n_in,
                              void* d_out, int out_size, void* d_ws, size_t ws_size,
                              hipStream_t stream)
{
    const float* x    = (const float*)d_in[0];
    const float* ea   = (const float*)d_in[1];
    const float* W_in = (const float*)d_in[2];
    const float* b_in = (const float*)d_in[3];
    const float* Wf   = (const float*)d_in[4];
    const float* bf   = (const float*)d_in[5];
    const float* Ws   = (const float*)d_in[6];
    const float* bs   = (const float*)d_in[7];
    const float* Wm   = (const float*)d_in[8];
    const float* bm   = (const float*)d_in[9];
    const int*   ei   = (const int*)d_in[10];   // [2][NE], row0=src, row1=dst

    // workspace layout (fp32): h | acc | P    -> 25.6 + 25.6 + 102.4 MB
    float* h   = (float*)d_ws;
    float* acc = h   + (size_t)NN * HID;
    float* P   = acc + (size_t)NN * HID;
    float* out = (float*)d_out;

    const dim3 blk(256);
    const dim3 gRows(782, 2, 1);   // ceil(50000/64) x (128/64)

    // h = relu(x @ W_in + b_in)
    k_gemm<FN, FN, true, true><<<gRows, blk, 0, stream>>>(x, NN, W_in, b_in, h, HID);

    for (int l = 0; l < 2; ++l) {
        const float* Wf_l = Wf + (size_t)l * 306 * HID;
        const float* Ws_l = Ws + (size_t)l * 306 * HID;

        // P[:,g*128:(g+1)*128] = h @ {Wf_i, Wf_j, Ws_i, Ws_j}
        k_gemm<HID, HID, false, false><<<gRows, blk, 0, stream>>>(h, NN, Wf_l,                nullptr, P + 0 * HID, 512);
        k_gemm<HID, HID, false, false><<<gRows, blk, 0, stream>>>(h, NN, Wf_l + 128 * HID,    nullptr, P + 1 * HID, 512);
        k_gemm<HID, HID, false, false><<<gRows, blk, 0, stream>>>(h, NN, Ws_l,                nullptr, P + 2 * HID, 512);
        k_gemm<HID, HID, false, false><<<gRows, blk, 0, stream>>>(h, NN, Ws_l + 128 * HID,    nullptr, P + 3 * HID, 512);

        // acc = h  (edge kernel accumulates messages on top)
        hipMemcpyAsync(acc, h, (size_t)NN * HID * sizeof(float),
                       hipMemcpyDeviceToDevice, stream);

        k_edge_msg<<<dim3(2048), blk, 0, stream>>>(
            P, ea, Wf_l + 256 * HID, Ws_l + 256 * HID,
            bf + l * HID, bs + l * HID, ei, ei + NE, acc);

        // h = relu(acc @ Wm_l + bm_l)   (final layer -> d_out)
        float* c0 = (l == 1) ? out : h;
        k_gemm<HID, HID, true, true><<<gRows, blk, 0, stream>>>(
            acc, NN, Wm + (size_t)l * HID * HID, bm + l * HID, c0, HID);
    }
    (void)in_sizes; (void)n_in; (void)out_size; (void)ws_size;
}

// Round 9
// 3622.931 us; speedup vs baseline: 1.0620x; 1.0620x over previous
//
#include <hip/hip_runtime.h>
#include <math.h>

#define NN 50000
#define NE 800000
#define FN 92
#define FE 50
#define HID 128

// ---------------------------------------------------------------- helpers
__device__ __forceinline__ float sigmoidf_(float x) {
    return 1.0f / (1.0f + __expf(-x));
}
__device__ __forceinline__ float softplusf_(float x) {
    // jax.nn.softplus = max(x,0) + log1p(exp(-|x|))
    return fmaxf(x, 0.0f) + __logf(1.0f + __expf(-fabsf(x)));
}
__device__ __forceinline__ float f4get(const float4& v, int i) {
    return i == 0 ? v.x : i == 1 ? v.y : i == 2 ? v.z : v.w;
}
__device__ __forceinline__ void atomAddF(float* p, float v) {
#if defined(__gfx90a__) || defined(__gfx940__) || defined(__gfx941__) || defined(__gfx942__) || defined(__gfx950__)
    unsafeAtomicAdd(p, v);
#else
    atomicAdd(p, v);
#endif
}

// ---------------------------------------------------------------- GEMM body
// C[64x64 tile] = act(A[M x K] @ B[K x 128] + bias). LDS-free, 256 threads,
// 4x4 register tile per thread. A/B reuse served by coalescer dedup + L1/L2.
template<int K, int LDA, bool BIAS, bool RELU>
__device__ __forceinline__ void gemm_body(
    const float* __restrict__ A, int M,
    const float* __restrict__ B,          // K x 128 row-major
    const float* __restrict__ bias,       // 128 (or null)
    float* __restrict__ C0, int ldc0,
    int r0, int cb)
{
    const int t  = threadIdx.x;
    const int tx = t & 15;
    const int ty = t >> 4;
    const int c4 = cb + (tx << 2);        // global col of 4-col group
    const int rr = r0 + (ty << 2);        // global row of 4-row group

    int ri[4];
#pragma unroll
    for (int i = 0; i < 4; ++i) ri[i] = (rr + i < M) ? (rr + i) : 0;

    float acc[4][4] = {};
#pragma unroll 2
    for (int k = 0; k < K; k += 4) {
        float4 a[4], b[4];
#pragma unroll
        for (int i = 0; i < 4; ++i)
            a[i] = *(const float4*)&A[(size_t)ri[i] * LDA + k];
#pragma unroll
        for (int j = 0; j < 4; ++j)
            b[j] = *(const float4*)&B[(size_t)(k + j) * 128 + c4];
#pragma unroll
        for (int kk = 0; kk < 4; ++kk)
#pragma unroll
            for (int i = 0; i < 4; ++i)
#pragma unroll
                for (int j = 0; j < 4; ++j)
                    acc[i][j] = fmaf(f4get(a[i], kk), f4get(b[kk], j), acc[i][j]);
    }

    float4 bb = make_float4(0.f, 0.f, 0.f, 0.f);
    if (BIAS) bb = *(const float4*)&bias[c4];
#pragma unroll
    for (int i = 0; i < 4; ++i) {
        const int r = rr + i;
        if (r < M) {
            float4 o;
            o.x = acc[i][0] + bb.x;
            o.y = acc[i][1] + bb.y;
            o.z = acc[i][2] + bb.z;
            o.w = acc[i][3] + bb.w;
            if (RELU) {
                o.x = fmaxf(o.x, 0.f); o.y = fmaxf(o.y, 0.f);
                o.z = fmaxf(o.z, 0.f); o.w = fmaxf(o.w, 0.f);
            }
            *(float4*)&C0[(size_t)r * ldc0 + c4] = o;
        }
    }
}

template<int K, int LDA, bool BIAS, bool RELU>
__global__ __launch_bounds__(256) void k_gemm(
    const float* __restrict__ A, int M,
    const float* __restrict__ B,
    const float* __restrict__ bias,
    float* __restrict__ C0, int ldc0)
{
    gemm_body<K, LDA, BIAS, RELU>(A, M, B, bias, C0, ldc0,
                                  blockIdx.x * 64, blockIdx.y * 64);
}

// All 4 node projections (Wf_i, Wf_j, Ws_i, Ws_j) in one launch.
// blockIdx.y: bit0 = column half, bits>=1 = which matrix (0..3).
__global__ __launch_bounds__(256) void k_gemm_p(
    const float* __restrict__ h,
    const float* __restrict__ Bf,    // Wf_l  (306 x 128, first 256 rows used)
    const float* __restrict__ Bs,    // Ws_l
    float* __restrict__ P)           // [NN][512]
{
    const int mm = blockIdx.y >> 1;  // 0..3
    const float* B = (mm < 2) ? (Bf + (size_t)mm * 128 * HID)
                              : (Bs + (size_t)(mm - 2) * 128 * HID);
    gemm_body<HID, HID, false, false>(h, NN, B, nullptr, P + mm * HID, 512,
                                      blockIdx.x * 64, (blockIdx.y & 1) * 64);
}

// ---------------------------------------------------------------- edge kernel
// 512 threads = 8 waves, 64 edges per batch (8 per wave). LDS: W (51.2 KB,
// both matrices) + eal[64][52] (padded for float4 k-reads) + indices = 65 KB
// -> 2 blocks/CU, 16 waves/CU. Thread map: eg = t>>6 (wave -> 8 edges),
// half = (t&63)>>5 (0: pf/sigmoid, 1: ps/softplus), c4 = 4-col group.
// sigmoid/softplus partners are lanes l and l^32 -> __shfl_xor, no LDS trip.
__global__ __launch_bounds__(512, 4) void k_edge_msg(
    const float* __restrict__ P,     // [NN][512]
    const float* __restrict__ ea,    // [NE][50]
    const float* __restrict__ Wfe,   // [50][128]
    const float* __restrict__ Wse,   // [50][128]
    const float* __restrict__ bfl,   // [128]
    const float* __restrict__ bsl,   // [128]
    const int*   __restrict__ esrc,
    const int*   __restrict__ edst,
    float*       __restrict__ accp)  // [NN][128], pre-initialized to h
{
    __shared__ float Wl[2 * 50 * 128];   // 51.2 KB
    __shared__ float eal[64 * 52];       // 13.3 KB, row stride 52 (16B aligned)
    __shared__ int   il0[64], il1[64];

    const int t = threadIdx.x;

    // stage Wf_e / Ws_e once per block
    for (int idx = t; idx < 1600; idx += 512) {
        const int k = idx >> 5, cq = (idx & 31) << 2;
        *(float4*)&Wl[k * 128 + cq]        = *(const float4*)&Wfe[k * 128 + cq];
        *(float4*)&Wl[6400 + k * 128 + cq] = *(const float4*)&Wse[k * 128 + cq];
    }

    const int half = (t & 63) >> 5;        // 0 -> pf, 1 -> ps
    const int c4   = (t & 31) << 2;
    const int eg   = t >> 6;               // wave id -> edge group of 8
    const float4 bb = *(const float4*)&((half ? bsl : bfl)[c4]);
    const float* WlW = Wl + half * 6400;
    const int pofs = half * 256;

    const int NB = NE / 64;                // 12500, exact
    for (int b = blockIdx.x; b < NB; b += gridDim.x) {
        const int e0 = b * 64;
        for (int idx = t; idx < 64 * 50; idx += 512) {
            const int r = idx / 50;
            eal[r * 52 + (idx - r * 50)] = ea[(size_t)e0 * 50 + idx];
        }
        if (t < 64)       il0[t]      = esrc[e0 + t];
        else if (t < 128) il1[t - 64] = edst[e0 + t - 64];
        __syncthreads();

        float m[8][4];
        // init with gathers + bias
#pragma unroll
        for (int ii = 0; ii < 8; ++ii) {
            const int le = eg * 8 + ii;
            const int d = il1[le], s = il0[le];
            const float4 g1 = *(const float4*)&P[(size_t)d * 512 + pofs + c4];
            const float4 g2 = *(const float4*)&P[(size_t)s * 512 + pofs + 128 + c4];
            m[ii][0] = g1.x + g2.x + bb.x;
            m[ii][1] = g1.y + g2.y + bb.y;
            m[ii][2] = g1.z + g2.z + bb.z;
            m[ii][3] = g1.w + g2.w + bb.w;
        }
        // + ea @ W_e, k-unrolled x4 with float4 e-reads
        for (int k = 0; k < 48; k += 4) {
            const float4 w0 = *(const float4*)&WlW[(k + 0) * 128 + c4];
            const float4 w1 = *(const float4*)&WlW[(k + 1) * 128 + c4];
            const float4 w2 = *(const float4*)&WlW[(k + 2) * 128 + c4];
            const float4 w3 = *(const float4*)&WlW[(k + 3) * 128 + c4];
#pragma unroll
            for (int ii = 0; ii < 8; ++ii) {
                const float4 ev = *(const float4*)&eal[(eg * 8 + ii) * 52 + k];
                m[ii][0] = fmaf(ev.x, w0.x, m[ii][0]);
                m[ii][1] = fmaf(ev.x, w0.y, m[ii][1]);
                m[ii][2] = fmaf(ev.x, w0.z, m[ii][2]);
                m[ii][3] = fmaf(ev.x, w0.w, m[ii][3]);
                m[ii][0] = fmaf(ev.y, w1.x, m[ii][0]);
                m[ii][1] = fmaf(ev.y, w1.y, m[ii][1]);
                m[ii][2] = fmaf(ev.y, w1.z, m[ii][2]);
                m[ii][3] = fmaf(ev.y, w1.w, m[ii][3]);
                m[ii][0] = fmaf(ev.z, w2.x, m[ii][0]);
                m[ii][1] = fmaf(ev.z, w2.y, m[ii][1]);
                m[ii][2] = fmaf(ev.z, w2.z, m[ii][2]);
                m[ii][3] = fmaf(ev.z, w2.w, m[ii][3]);
                m[ii][0] = fmaf(ev.w, w3.x, m[ii][0]);
                m[ii][1] = fmaf(ev.w, w3.y, m[ii][1]);
                m[ii][2] = fmaf(ev.w, w3.z, m[ii][2]);
                m[ii][3] = fmaf(ev.w, w3.w, m[ii][3]);
            }
        }
        // tail k = 48, 49 (float2 e-read, 8B aligned: 52*4=208 ≡ 0 mod 8)
        {
            const float4 w0 = *(const float4*)&WlW[48 * 128 + c4];
            const float4 w1 = *(const float4*)&WlW[49 * 128 + c4];
#pragma unroll
            for (int ii = 0; ii < 8; ++ii) {
                const float2 ev = *(const float2*)&eal[(eg * 8 + ii) * 52 + 48];
                m[ii][0] = fmaf(ev.x, w0.x, m[ii][0]);
                m[ii][1] = fmaf(ev.x, w0.y, m[ii][1]);
                m[ii][2] = fmaf(ev.x, w0.z, m[ii][2]);
                m[ii][3] = fmaf(ev.x, w0.w, m[ii][3]);
                m[ii][0] = fmaf(ev.y, w1.x, m[ii][0]);
                m[ii][1] = fmaf(ev.y, w1.y, m[ii][1]);
                m[ii][2] = fmaf(ev.y, w1.z, m[ii][2]);
                m[ii][3] = fmaf(ev.y, w1.w, m[ii][3]);
            }
        }
        // activation + cross-half exchange + product
#pragma unroll
        for (int ii = 0; ii < 8; ++ii) {
#pragma unroll
            for (int j = 0; j < 4; ++j) {
                const float v = m[ii][j];
                const float a = half ? softplusf_(v) : sigmoidf_(v);
                const float o = __shfl_xor(a, 32, 64);
                m[ii][j] = a * o;          // sigmoid(pf)*softplus(ps), both halves
            }
        }
        // scatter: half 0 handles edges 0..3 of its group, half 1 edges 4..7
        if (half == 0) {
#pragma unroll
            for (int q = 0; q < 4; ++q) {
                const int d = il1[eg * 8 + q];
                float* p = accp + (size_t)d * 128 + c4;
                atomAddF(p + 0, m[q][0]);
                atomAddF(p + 1, m[q][1]);
                atomAddF(p + 2, m[q][2]);
                atomAddF(p + 3, m[q][3]);
            }
        } else {
#pragma unroll
            for (int q = 0; q < 4; ++q) {
                const int d = il1[eg * 8 + 4 + q];
                float* p = accp + (size_t)d * 128 + c4;
                atomAddF(p + 0, m[4 + q][0]);
                atomAddF(p + 1, m[4 + q][1]);
                atomAddF(p + 2, m[4 + q][2]);
                atomAddF(p + 3, m[4 + q][3]);
            }
        }
        __syncthreads();   // protect eal/il before next batch
    }
}

// ---------------------------------------------------------------- launcher
extern "C" void kernel_launch(void* const* d_in, const int* in_sizes, int n_in,
                              void* d_out, int out_size, void* d_ws, size_t ws_size,
                              hipStream_t stream)
{
    const float* x    = (const float*)d_in[0];
    const float* ea   = (const float*)d_in[1];
    const float* W_in = (const float*)d_in[2];
    const float* b_in = (const float*)d_in[3];
    const float* Wf   = (const float*)d_in[4];
    const float* bf   = (const float*)d_in[5];
    const float* Ws   = (const float*)d_in[6];
    const float* bs   = (const float*)d_in[7];
    const float* Wm   = (const float*)d_in[8];
    const float* bm   = (const float*)d_in[9];
    const int*   ei   = (const int*)d_in[10];   // [2][NE], row0=src, row1=dst

    // workspace layout (fp32): h | acc | P    -> 25.6 + 25.6 + 102.4 MB
    float* h   = (float*)d_ws;
    float* acc = h   + (size_t)NN * HID;
    float* P   = acc + (size_t)NN * HID;
    float* out = (float*)d_out;

    const dim3 blk(256);
    const dim3 gRows(782, 2, 1);   // ceil(50000/64) x (128/64)

    // h = relu(x @ W_in + b_in)
    k_gemm<FN, FN, true, true><<<gRows, blk, 0, stream>>>(x, NN, W_in, b_in, h, HID);

    for (int l = 0; l < 2; ++l) {
        const float* Wf_l = Wf + (size_t)l * 306 * HID;
        const float* Ws_l = Ws + (size_t)l * 306 * HID;

        // P[:, m*128:(m+1)*128] = h @ {Wf_i, Wf_j, Ws_i, Ws_j} — one launch
        k_gemm_p<<<dim3(782, 8), blk, 0, stream>>>(h, Wf_l, Ws_l, P);

        // acc = h  (edge kernel accumulates messages on top)
        hipMemcpyAsync(acc, h, (size_t)NN * HID * sizeof(float),
                       hipMemcpyDeviceToDevice, stream);

        k_edge_msg<<<dim3(2048), dim3(512), 0, stream>>>(
            P, ea, Wf_l + 256 * HID, Ws_l + 256 * HID,
            bf + l * HID, bs + l * HID, ei, ei + NE, acc);

        // h = relu(acc @ Wm_l + bm_l)   (final layer -> d_out)
        float* c0 = (l == 1) ? out : h;
        k_gemm<HID, HID, true, true><<<gRows, blk, 0, stream>>>(
            acc, NN, Wm + (size_t)l * HID * HID, bm + l * HID, c0, HID);
    }
    (void)in_sizes; (void)n_in; (void)out_size; (void)ws_size;
}